// Round 1
// baseline (226.035 us; speedup 1.0000x reference)
//
#include <hip/hip_runtime.h>

#define B_  16
#define S_  512
#define H_  768
#define T_  9
#define HD_ 64
#define N1  (T_*HD_*2)   // 1152
#define M1  (B_*S_)      // 8192

typedef __attribute__((ext_vector_type(8))) short bf16x8;
typedef __attribute__((ext_vector_type(4))) float f32x4;

__device__ inline short f2bf(float f){
  union { float f; unsigned u; } v; v.f = f;
  unsigned r = v.u + 0x7fffu + ((v.u >> 16) & 1u);   // RNE
  return (short)(r >> 16);
}

// --- prep: W [768,1152] fp32 -> Wt [1152,768] bf16 (transposed) ---
__global__ void prep_w(const float* __restrict__ W, short* __restrict__ Wt){
  int i = blockIdx.x*256 + threadIdx.x;
  if(i >= N1*H_) return;
  int n = i / H_, k = i - n*H_;
  Wt[i] = f2bf(W[k*N1 + n]);
}

// --- prep: cos/sin table [S][32] (accurate libm, one-time) ---
__global__ void prep_trig(float2* __restrict__ tab){
  int i = blockIdx.x*256 + threadIdx.x;
  if(i >= S_*32) return;
  int s = i >> 5, p = i & 31;
  float inv = powf(10000.f, -2.f*(float)p/64.f);
  float a = (float)s * inv;
  tab[i] = make_float2(cosf(a), sinf(a));
}

// --- GEMM1 [8192,768]x[768,1152] + bias + RoPE -> Qr,Kr bf16 [B*T, S, 64] ---
__global__ __launch_bounds__(256) void gemm1_rope(
    const float* __restrict__ hs, const short* __restrict__ Wt,
    const float* __restrict__ bias, const float2* __restrict__ tab,
    short* __restrict__ Qr, short* __restrict__ Kr)
{
  const int lane = threadIdx.x & 63;
  const int w    = threadIdx.x >> 6;
  const int n0   = blockIdx.x * 64;
  const int m0   = blockIdx.y * 64 + w * 16;
  const int lr   = lane & 15;          // A-row / B-col within 16
  const int lk   = (lane >> 4) * 8;    // k sub-offset

  f32x4 acc[4] = {f32x4{0,0,0,0}, f32x4{0,0,0,0}, f32x4{0,0,0,0}, f32x4{0,0,0,0}};
  const float* arow = hs + (size_t)(m0 + lr) * H_;

  for(int k0 = 0; k0 < H_; k0 += 32){
    int ka = k0 + lk;
    float4 a0 = *(const float4*)(arow + ka);
    float4 a1 = *(const float4*)(arow + ka + 4);
    bf16x8 af;
    af[0]=f2bf(a0.x); af[1]=f2bf(a0.y); af[2]=f2bf(a0.z); af[3]=f2bf(a0.w);
    af[4]=f2bf(a1.x); af[5]=f2bf(a1.y); af[6]=f2bf(a1.z); af[7]=f2bf(a1.w);
    #pragma unroll
    for(int c = 0; c < 4; ++c){
      bf16x8 bfr = *(const bf16x8*)(Wt + (size_t)(n0 + c*16 + lr) * H_ + ka);
      acc[c] = __builtin_amdgcn_mfma_f32_16x16x32_bf16(af, bfr, acc[c], 0, 0, 0);
    }
  }

  // epilogue: bias + RoPE (pair partner is exactly lane^2) + scatter bf16
  const int rbase = m0 + (lane >> 4) * 4;
  #pragma unroll
  for(int c = 0; c < 4; ++c){
    int n  = n0 + c*16 + lr;
    float bv = bias[n];
    int t   = n >> 7;          // head type
    int hd  = (n >> 1) & 63;   // head dim
    int p   = hd >> 1;         // pair index
    int odd = hd & 1;
    int qk  = n & 1;           // 0=q, 1=k
    #pragma unroll
    for(int j = 0; j < 4; ++j){
      int m  = rbase + j;
      int bi = m >> 9, sp = m & 511;
      float v  = acc[c][j] + bv;
      float pv = __shfl_xor(v, 2);             // partner element of the RoPE pair
      float2 cs = tab[sp*32 + p];
      float rot = odd ? fmaf(v, cs.x,  pv*cs.y)
                      : fmaf(v, cs.x, -pv*cs.y);
      short* dst = (qk ? Kr : Qr) + ((size_t)(bi*T_ + t)*S_ + sp)*HD_ + hd;
      *dst = f2bf(rot);
    }
  }
}

// --- biaffine: per (b,t) Q[512,64] . K^T -> logits [512,512] + masks ---
__global__ __launch_bounds__(256) void gemm2_mask(
    const short* __restrict__ Qr, const short* __restrict__ Kr,
    const int* __restrict__ am, float* __restrict__ out)
{
  const int lane = threadIdx.x & 63;
  const int w    = threadIdx.x >> 6;
  const int bt   = blockIdx.z;
  const int n0   = blockIdx.x * 64;
  const int m0   = blockIdx.y * 64 + w * 16;
  const int lr   = lane & 15;
  const int lk   = (lane >> 4) * 8;
  const int b    = bt / T_;

  const short* Q = Qr + (size_t)bt * S_ * HD_;
  const short* K = Kr + (size_t)bt * S_ * HD_;
  f32x4 acc[4] = {f32x4{0,0,0,0}, f32x4{0,0,0,0}, f32x4{0,0,0,0}, f32x4{0,0,0,0}};

  #pragma unroll
  for(int ks = 0; ks < HD_; ks += 32){
    bf16x8 af = *(const bf16x8*)(Q + (size_t)(m0 + lr)*HD_ + ks + lk);
    #pragma unroll
    for(int c = 0; c < 4; ++c){
      bf16x8 bfr = *(const bf16x8*)(K + (size_t)(n0 + c*16 + lr)*HD_ + ks + lk);
      acc[c] = __builtin_amdgcn_mfma_f32_16x16x32_bf16(af, bfr, acc[c], 0, 0, 0);
    }
  }

  const int rbase = m0 + (lane >> 4) * 4;
  const int* amb  = am + b * S_;
  #pragma unroll
  for(int c = 0; c < 4; ++c){
    int n = n0 + c*16 + lr;
    float amn = (float)amb[n];
    #pragma unroll
    for(int j = 0; j < 4; ++j){
      int m = rbase + j;
      float amm = (float)amb[m];
      float v = acc[c][j] * 0.125f;          // 1/sqrt(64)
      v -= (1.f - amm*amn) * 1e12f;          // pad mask
      if(n < m) v -= 1e12f;                  // (1 - triu) mask
      out[((size_t)bt*S_ + m)*S_ + n] = v;
    }
  }
}

extern "C" void kernel_launch(void* const* d_in, const int* in_sizes, int n_in,
                              void* d_out, int out_size, void* d_ws, size_t ws_size,
                              hipStream_t stream)
{
  const float* hs    = (const float*)d_in[0];
  const int*   amask = (const int*)  d_in[1];
  const float* W     = (const float*)d_in[2];
  const float* bias  = (const float*)d_in[3];
  float* out = (float*)d_out;

  char* ws = (char*)d_ws;
  short*  Wt  = (short*) (ws);                                  // 1,769,472 B
  float2* tab = (float2*)(ws + 1769472);                        //   131,072 B
  short*  Qr  = (short*) (ws + 1769472 + 131072);               // 9,437,184 B
  short*  Kr  = (short*) (ws + 1769472 + 131072 + 9437184);     // 9,437,184 B

  prep_w   <<<(N1*H_ + 255)/256, 256, 0, stream>>>(W, Wt);
  prep_trig<<<(S_*32 + 255)/256, 256, 0, stream>>>(tab);
  gemm1_rope<<<dim3(N1/64, M1/64), 256, 0, stream>>>(hs, Wt, bias, tab, Qr, Kr);
  gemm2_mask<<<dim3(S_/64, S_/64, B_*T_), 256, 0, stream>>>(Qr, Kr, amask, out);
}

// Round 2
// 120.050 us; speedup vs baseline: 1.8828x; 1.8828x over previous
//
#include <hip/hip_runtime.h>

#define B_  16
#define S_  512
#define H_  768
#define T_  9
#define HD_ 64
#define N1  (T_*HD_*2)   // 1152
#define M1  (B_*S_)      // 8192

typedef __attribute__((ext_vector_type(8))) short bf16x8;
typedef __attribute__((ext_vector_type(4))) float f32x4;

#define GLB(p) ((const __attribute__((address_space(1))) void*)(p))
#define LDSP(p) ((__attribute__((address_space(3))) void*)(p))

__device__ inline short f2bf(float f){
  union { float f; unsigned u; } v; v.f = f;
  unsigned r = v.u + 0x7fffu + ((v.u >> 16) & 1u);   // RNE
  return (short)(r >> 16);
}

// --- prep: hidden_states fp32 -> bf16 [8192][768] ---
__global__ __launch_bounds__(256) void prep_hs(const float* __restrict__ hs,
                                               short* __restrict__ Abf){
  int i = (blockIdx.x*256 + threadIdx.x) * 8;
  float4 a0 = *(const float4*)(hs + i);
  float4 a1 = *(const float4*)(hs + i + 4);
  bf16x8 r;
  r[0]=f2bf(a0.x); r[1]=f2bf(a0.y); r[2]=f2bf(a0.z); r[3]=f2bf(a0.w);
  r[4]=f2bf(a1.x); r[5]=f2bf(a1.y); r[6]=f2bf(a1.z); r[7]=f2bf(a1.w);
  *(bf16x8*)(Abf + i) = r;
}

// --- prep: W [768,1152] fp32 -> Wt [1152,768] bf16, LDS-tiled transpose ---
__global__ __launch_bounds__(256) void prep_w(const float* __restrict__ W,
                                              short* __restrict__ Wt){
  __shared__ float tile[32][33];
  int n0 = blockIdx.x*32, k0 = blockIdx.y*32;
  int tx = threadIdx.x & 31, ty = threadIdx.x >> 5;   // ty 0..7
  #pragma unroll
  for(int r = 0; r < 32; r += 8)
    tile[ty + r][tx] = W[(size_t)(k0 + ty + r)*N1 + n0 + tx];
  __syncthreads();
  #pragma unroll
  for(int r = 0; r < 32; r += 8)
    Wt[(size_t)(n0 + ty + r)*H_ + k0 + tx] = f2bf(tile[tx][ty + r]);
}

// --- prep: cos/sin table [S][32] ---
__global__ void prep_trig(float2* __restrict__ tab){
  int i = blockIdx.x*256 + threadIdx.x;
  if(i >= S_*32) return;
  int s = i >> 5, p = i & 31;
  float inv = powf(10000.f, -2.f*(float)p/64.f);
  float a = (float)s * inv;
  tab[i] = make_float2(cosf(a), sinf(a));
}

// --- GEMM1: m97 structure. [8192,768]x[768,1152] + bias + RoPE -> Qr,Kr ---
__global__ __launch_bounds__(256) void gemm1_rope(
    const short* __restrict__ Abf, const short* __restrict__ Wt,
    const float* __restrict__ bias, const float2* __restrict__ tab,
    short* __restrict__ Qr, short* __restrict__ Kr)
{
  __shared__ short As[128*32];
  __shared__ short Bs[128*32];
  const int tid  = threadIdx.x;
  const int lane = tid & 63, w = tid >> 6;
  const int wm = (w >> 1) * 64, wn = (w & 1) * 64;
  const int m0 = blockIdx.x * 128, n0 = blockIdx.y * 128;
  const int lr = lane & 15, lk = (lane >> 4) * 8;

  // staging: thread covers row tid>>2 (0..63), 16B slot tid&3; two issues = 128 rows
  const int sr = tid >> 2;
  const int sc = (tid & 3) * 8;
  const short* aS = Abf + (size_t)(m0 + sr) * H_ + sc;
  const short* bS = Wt  + (size_t)(n0 + sr) * H_ + sc;
  short* aD = As + tid * 8;
  short* bD = Bs + tid * 8;

  f32x4 acc[4][4] = {};

  for(int k0 = 0; k0 < H_; k0 += 32){
    __syncthreads();
    __builtin_amdgcn_global_load_lds(GLB(aS + k0),           LDSP(aD),        16, 0, 0);
    __builtin_amdgcn_global_load_lds(GLB(aS + 64*H_ + k0),   LDSP(aD + 2048), 16, 0, 0);
    __builtin_amdgcn_global_load_lds(GLB(bS + k0),           LDSP(bD),        16, 0, 0);
    __builtin_amdgcn_global_load_lds(GLB(bS + 64*H_ + k0),   LDSP(bD + 2048), 16, 0, 0);
    __syncthreads();

    bf16x8 aF[4], bF[4];
    #pragma unroll
    for(int i = 0; i < 4; ++i) aF[i] = *(const bf16x8*)(As + (wm + i*16 + lr)*32 + lk);
    #pragma unroll
    for(int j = 0; j < 4; ++j) bF[j] = *(const bf16x8*)(Bs + (wn + j*16 + lr)*32 + lk);
    #pragma unroll
    for(int i = 0; i < 4; ++i)
      #pragma unroll
      for(int j = 0; j < 4; ++j)
        acc[i][j] = __builtin_amdgcn_mfma_f32_16x16x32_bf16(aF[i], bF[j], acc[i][j], 0, 0, 0);
  }

  // epilogue: bias + RoPE (partner = lane^2) + bf16 scatter
  const int rb = m0 + wm + (lane >> 4) * 4;
  #pragma unroll
  for(int j = 0; j < 4; ++j){
    int n = n0 + wn + j*16 + lr;
    float bv = bias[n];
    int t = n >> 7, hd = (n >> 1) & 63, p = hd >> 1, odd = hd & 1, qk = n & 1;
    short* base = qk ? Kr : Qr;
    #pragma unroll
    for(int i = 0; i < 4; ++i){
      #pragma unroll
      for(int jj = 0; jj < 4; ++jj){
        int m = rb + i*16 + jj;
        int bi = m >> 9, sp = m & 511;
        float v  = acc[i][j][jj] + bv;
        float pv = __shfl_xor(v, 2);
        float2 cs = tab[sp*32 + p];
        float rot = odd ? fmaf(v, cs.x,  pv*cs.y)
                        : fmaf(v, cs.x, -pv*cs.y);
        base[((size_t)(bi*T_ + t)*S_ + sp)*HD_ + hd] = f2bf(rot);
      }
    }
  }
}

// --- biaffine: per (b,t) Q[512,64] . K^T -> logits [512,512] + masks ---
__global__ __launch_bounds__(256) void gemm2_mask(
    const short* __restrict__ Qr, const short* __restrict__ Kr,
    const int* __restrict__ am, float* __restrict__ out)
{
  const int lane = threadIdx.x & 63;
  const int w    = threadIdx.x >> 6;
  const int bt   = blockIdx.z;
  const int n0   = blockIdx.x * 64;
  const int m0   = blockIdx.y * 64 + w * 16;
  const int lr   = lane & 15;
  const int lk   = (lane >> 4) * 8;
  const int b    = bt / T_;

  const short* Q = Qr + (size_t)bt * S_ * HD_;
  const short* K = Kr + (size_t)bt * S_ * HD_;
  f32x4 acc[4] = {f32x4{0,0,0,0}, f32x4{0,0,0,0}, f32x4{0,0,0,0}, f32x4{0,0,0,0}};

  #pragma unroll
  for(int ks = 0; ks < HD_; ks += 32){
    bf16x8 af = *(const bf16x8*)(Q + (size_t)(m0 + lr)*HD_ + ks + lk);
    #pragma unroll
    for(int c = 0; c < 4; ++c){
      bf16x8 bfr = *(const bf16x8*)(K + (size_t)(n0 + c*16 + lr)*HD_ + ks + lk);
      acc[c] = __builtin_amdgcn_mfma_f32_16x16x32_bf16(af, bfr, acc[c], 0, 0, 0);
    }
  }

  const int rbase = m0 + (lane >> 4) * 4;
  const int* amb  = am + b * S_;
  #pragma unroll
  for(int c = 0; c < 4; ++c){
    int n = n0 + c*16 + lr;
    float amn = (float)amb[n];
    #pragma unroll
    for(int j = 0; j < 4; ++j){
      int m = rbase + j;
      float amm = (float)amb[m];
      float v = acc[c][j] * 0.125f;
      v -= (1.f - amm*amn) * 1e12f;
      if(n < m) v -= 1e12f;
      out[((size_t)bt*S_ + m)*S_ + n] = v;
    }
  }
}

extern "C" void kernel_launch(void* const* d_in, const int* in_sizes, int n_in,
                              void* d_out, int out_size, void* d_ws, size_t ws_size,
                              hipStream_t stream)
{
  const float* hs    = (const float*)d_in[0];
  const int*   amask = (const int*)  d_in[1];
  const float* W     = (const float*)d_in[2];
  const float* bias  = (const float*)d_in[3];
  float* out = (float*)d_out;

  char* ws = (char*)d_ws;
  short*  Wt  = (short*) (ws);                       // 1,769,472 B
  float2* tab = (float2*)(ws + 1769472);             //   131,072 B
  short*  Qr  = (short*) (ws + 1900544);             // 9,437,184 B
  short*  Kr  = (short*) (ws + 11337728);            // 9,437,184 B
  short*  Abf = (short*) (ws + 20774912);            // 12,582,912 B  (end 33,357,824)

  prep_hs  <<<M1*H_/2048, 256, 0, stream>>>(hs, Abf);
  prep_w   <<<dim3(N1/32, H_/32), 256, 0, stream>>>(W, Wt);
  prep_trig<<<(S_*32 + 255)/256, 256, 0, stream>>>(tab);
  gemm1_rope<<<dim3(M1/128, N1/128), 256, 0, stream>>>(Abf, Wt, bias, tab, Qr, Kr);
  gemm2_mask<<<dim3(S_/64, S_/64, B_*T_), 256, 0, stream>>>(Qr, Kr, amask, out);
}

// Round 3
// 105.169 us; speedup vs baseline: 2.1493x; 1.1415x over previous
//
#include <hip/hip_runtime.h>

#define B_  16
#define S_  512
#define H_  768
#define T_  9
#define HD_ 64
#define N1  (T_*HD_*2)   // 1152
#define M1  (B_*S_)      // 8192

typedef __attribute__((ext_vector_type(8))) short bf16x8;
typedef __attribute__((ext_vector_type(4))) float f32x4;

#define GLB(p) ((const __attribute__((address_space(1))) void*)(p))
#define LDSP(p) ((__attribute__((address_space(3))) void*)(p))

__device__ inline short f2bf(float f){
  union { float f; unsigned u; } v; v.f = f;
  unsigned r = v.u + 0x7fffu + ((v.u >> 16) & 1u);   // RNE
  return (short)(r >> 16);
}

// --- merged prep: hs->bf16 | W transpose->bf16 | trig table ---
// blocks [0,3072): prep_hs; [3072,3936): prep_w; [3936,4000): trig
__global__ __launch_bounds__(256) void prep_all(
    const float* __restrict__ hs, short* __restrict__ Abf,
    const float* __restrict__ W, short* __restrict__ Wt,
    float2* __restrict__ tab)
{
  __shared__ float tile[32][33];
  const int bx = blockIdx.x, tid = threadIdx.x;
  if(bx < 3072){
    int i = bx*2048 + tid*8;
    float4 a0 = *(const float4*)(hs + i);
    float4 a1 = *(const float4*)(hs + i + 4);
    bf16x8 r;
    r[0]=f2bf(a0.x); r[1]=f2bf(a0.y); r[2]=f2bf(a0.z); r[3]=f2bf(a0.w);
    r[4]=f2bf(a1.x); r[5]=f2bf(a1.y); r[6]=f2bf(a1.z); r[7]=f2bf(a1.w);
    *(bf16x8*)(Abf + i) = r;
  } else if(bx < 3936){
    int idx = bx - 3072;
    int n0 = (idx % 36)*32, k0 = (idx / 36)*32;
    int tx = tid & 31, ty = tid >> 5;   // ty 0..7
    #pragma unroll
    for(int r = 0; r < 32; r += 8)
      tile[ty + r][tx] = W[(size_t)(k0 + ty + r)*N1 + n0 + tx];
    __syncthreads();
    #pragma unroll
    for(int r = 0; r < 32; r += 8)
      Wt[(size_t)(n0 + ty + r)*H_ + k0 + tx] = f2bf(tile[tx][ty + r]);
  } else {
    int i = (bx - 3936)*256 + tid;      // 64 blocks * 256 = 512*32
    int s = i >> 5, p = i & 31;
    float inv = powf(10000.f, -2.f*(float)p/64.f);
    float a = (float)s * inv;
    tab[i] = make_float2(cosf(a), sinf(a));
  }
}

// --- GEMM1: m97 structure. [8192,768]x[768,1152] + bias + RoPE -> Qr,Kr ---
__global__ __launch_bounds__(256) void gemm1_rope(
    const short* __restrict__ Abf, const short* __restrict__ Wt,
    const float* __restrict__ bias, const float2* __restrict__ tab,
    short* __restrict__ Qr, short* __restrict__ Kr)
{
  __shared__ short As[128*32];
  __shared__ short Bs[128*32];
  const int tid  = threadIdx.x;
  const int lane = tid & 63, w = tid >> 6;
  const int wm = (w >> 1) * 64, wn = (w & 1) * 64;
  const int m0 = blockIdx.x * 128, n0 = blockIdx.y * 128;
  const int lr = lane & 15, lk = (lane >> 4) * 8;

  const int sr = tid >> 2;
  const int sc = (tid & 3) * 8;
  const short* aS = Abf + (size_t)(m0 + sr) * H_ + sc;
  const short* bS = Wt  + (size_t)(n0 + sr) * H_ + sc;
  short* aD = As + tid * 8;
  short* bD = Bs + tid * 8;

  f32x4 acc[4][4] = {};

  for(int k0 = 0; k0 < H_; k0 += 32){
    __syncthreads();
    __builtin_amdgcn_global_load_lds(GLB(aS + k0),           LDSP(aD),        16, 0, 0);
    __builtin_amdgcn_global_load_lds(GLB(aS + 64*H_ + k0),   LDSP(aD + 2048), 16, 0, 0);
    __builtin_amdgcn_global_load_lds(GLB(bS + k0),           LDSP(bD),        16, 0, 0);
    __builtin_amdgcn_global_load_lds(GLB(bS + 64*H_ + k0),   LDSP(bD + 2048), 16, 0, 0);
    __syncthreads();

    bf16x8 aF[4], bF[4];
    #pragma unroll
    for(int i = 0; i < 4; ++i) aF[i] = *(const bf16x8*)(As + (wm + i*16 + lr)*32 + lk);
    #pragma unroll
    for(int j = 0; j < 4; ++j) bF[j] = *(const bf16x8*)(Bs + (wn + j*16 + lr)*32 + lk);
    #pragma unroll
    for(int i = 0; i < 4; ++i)
      #pragma unroll
      for(int j = 0; j < 4; ++j)
        acc[i][j] = __builtin_amdgcn_mfma_f32_16x16x32_bf16(aF[i], bF[j], acc[i][j], 0, 0, 0);
  }

  const int rb = m0 + wm + (lane >> 4) * 4;
  #pragma unroll
  for(int j = 0; j < 4; ++j){
    int n = n0 + wn + j*16 + lr;
    float bv = bias[n];
    int t = n >> 7, hd = (n >> 1) & 63, p = hd >> 1, odd = hd & 1, qk = n & 1;
    short* base = qk ? Kr : Qr;
    #pragma unroll
    for(int i = 0; i < 4; ++i){
      #pragma unroll
      for(int jj = 0; jj < 4; ++jj){
        int m = rb + i*16 + jj;
        int bi = m >> 9, sp = m & 511;
        float v  = acc[i][j][jj] + bv;
        float pv = __shfl_xor(v, 2);
        float2 cs = tab[sp*32 + p];
        float rot = odd ? fmaf(v, cs.x,  pv*cs.y)
                        : fmaf(v, cs.x, -pv*cs.y);
        base[((size_t)(bi*T_ + t)*S_ + sp)*HD_ + hd] = f2bf(rot);
      }
    }
  }
}

// --- biaffine: per (b,t) Q[512,64].K^T -> [512,512], 128x128/block ---
__global__ __launch_bounds__(256) void gemm2_mask(
    const short* __restrict__ Qr, const short* __restrict__ Kr,
    const int* __restrict__ am, float* __restrict__ out)
{
  const int lane = threadIdx.x & 63;
  const int w    = threadIdx.x >> 6;
  const int bt   = blockIdx.z;
  const int b    = bt / T_;
  const int n0   = blockIdx.x * 128 + (w & 1) * 64;
  const int m0   = blockIdx.y * 128 + (w >> 1) * 64;
  const int lr   = lane & 15;
  const int lk   = (lane >> 4) * 8;

  const short* Q = Qr + (size_t)bt * S_ * HD_;
  const short* K = Kr + (size_t)bt * S_ * HD_;
  f32x4 acc[4][4] = {};

  #pragma unroll
  for(int ks = 0; ks < HD_; ks += 32){
    bf16x8 aF[4], bF[4];
    #pragma unroll
    for(int i = 0; i < 4; ++i) aF[i] = *(const bf16x8*)(Q + (size_t)(m0 + i*16 + lr)*HD_ + ks + lk);
    #pragma unroll
    for(int j = 0; j < 4; ++j) bF[j] = *(const bf16x8*)(K + (size_t)(n0 + j*16 + lr)*HD_ + ks + lk);
    #pragma unroll
    for(int i = 0; i < 4; ++i)
      #pragma unroll
      for(int j = 0; j < 4; ++j)
        acc[i][j] = __builtin_amdgcn_mfma_f32_16x16x32_bf16(aF[i], bF[j], acc[i][j], 0, 0, 0);
  }

  const int rbase = m0 + (lane >> 4) * 4;
  const int* amb  = am + b * S_;
  #pragma unroll
  for(int j = 0; j < 4; ++j){
    int n = n0 + j*16 + lr;
    float amn = (float)amb[n];
    #pragma unroll
    for(int i = 0; i < 4; ++i){
      #pragma unroll
      for(int jj = 0; jj < 4; ++jj){
        int m = rbase + i*16 + jj;
        float amm = (float)amb[m];
        float v = acc[i][j][jj] * 0.125f;
        v -= (1.f - amm*amn) * 1e12f;
        if(n < m) v -= 1e12f;
        out[((size_t)bt*S_ + m)*S_ + n] = v;
      }
    }
  }
}

extern "C" void kernel_launch(void* const* d_in, const int* in_sizes, int n_in,
                              void* d_out, int out_size, void* d_ws, size_t ws_size,
                              hipStream_t stream)
{
  const float* hs    = (const float*)d_in[0];
  const int*   amask = (const int*)  d_in[1];
  const float* W     = (const float*)d_in[2];
  const float* bias  = (const float*)d_in[3];
  float* out = (float*)d_out;

  char* ws = (char*)d_ws;
  short*  Wt  = (short*) (ws);                       // 1,769,472 B
  float2* tab = (float2*)(ws + 1769472);             //   131,072 B
  short*  Qr  = (short*) (ws + 1900544);             // 9,437,184 B
  short*  Kr  = (short*) (ws + 11337728);            // 9,437,184 B
  short*  Abf = (short*) (ws + 20774912);            // 12,582,912 B

  prep_all <<<4000, 256, 0, stream>>>(hs, Abf, W, Wt, tab);
  gemm1_rope<<<dim3(M1/128, N1/128), 256, 0, stream>>>(Abf, Wt, bias, tab, Qr, Kr);
  gemm2_mask<<<dim3(S_/128, S_/128, B_*T_), 256, 0, stream>>>(Qr, Kr, amask, out);
}

// Round 4
// 102.515 us; speedup vs baseline: 2.2049x; 1.0259x over previous
//
#include <hip/hip_runtime.h>

#define B_  16
#define S_  512
#define H_  768
#define T_  9
#define HD_ 64
#define N1  (T_*HD_*2)   // 1152
#define M1  (B_*S_)      // 8192

typedef __attribute__((ext_vector_type(8))) short bf16x8;
typedef __attribute__((ext_vector_type(4))) float f32x4;

#define GLB(p) ((const __attribute__((address_space(1))) void*)(p))
#define LDSP(p) ((__attribute__((address_space(3))) void*)(p))

__device__ inline unsigned short f2bf(float f){
  union { float f; unsigned u; } v; v.f = f;
  unsigned r = v.u + 0x7fffu + ((v.u >> 16) & 1u);   // RNE
  return (unsigned short)(r >> 16);
}

// --- merged prep: hs->bf16 | W transpose->bf16 | trig table ---
// blocks [0,3072): prep_hs; [3072,3936): prep_w; [3936,4000): trig
__global__ __launch_bounds__(256) void prep_all(
    const float* __restrict__ hs, short* __restrict__ Abf,
    const float* __restrict__ W, short* __restrict__ Wt,
    float2* __restrict__ tab)
{
  __shared__ float tile[32][33];
  const int bx = blockIdx.x, tid = threadIdx.x;
  if(bx < 3072){
    int i = bx*2048 + tid*8;
    float4 a0 = *(const float4*)(hs + i);
    float4 a1 = *(const float4*)(hs + i + 4);
    bf16x8 r;
    r[0]=f2bf(a0.x); r[1]=f2bf(a0.y); r[2]=f2bf(a0.z); r[3]=f2bf(a0.w);
    r[4]=f2bf(a1.x); r[5]=f2bf(a1.y); r[6]=f2bf(a1.z); r[7]=f2bf(a1.w);
    *(bf16x8*)(Abf + i) = r;
  } else if(bx < 3936){
    int idx = bx - 3072;
    int n0 = (idx % 36)*32, k0 = (idx / 36)*32;
    int tx = tid & 31, ty = tid >> 5;   // ty 0..7
    #pragma unroll
    for(int r = 0; r < 32; r += 8)
      tile[ty + r][tx] = W[(size_t)(k0 + ty + r)*N1 + n0 + tx];
    __syncthreads();
    #pragma unroll
    for(int r = 0; r < 32; r += 8)
      Wt[(size_t)(n0 + ty + r)*H_ + k0 + tx] = f2bf(tile[tx][ty + r]);
  } else {
    int i = (bx - 3936)*256 + tid;      // 64 blocks * 256 = 512*32
    int s = i >> 5, p = i & 31;
    float inv = powf(10000.f, -2.f*(float)p/64.f);
    float a = (float)s * inv;
    tab[i] = make_float2(cosf(a), sinf(a));
  }
}

// --- GEMM1 (swapped operands): out cols = m (lane&15), rows = n (regs) ---
// n-tile of 128 == exactly one entity type t; per lane the 4 regs are
// {q(hd0), k(hd0), q(hd0+1), k(hd0+1)} -> RoPE pair is lane-local.
__global__ __launch_bounds__(256) void gemm1_rope(
    const short* __restrict__ Abf, const short* __restrict__ Wt,
    const float* __restrict__ bias, const float2* __restrict__ tab,
    short* __restrict__ Qr, short* __restrict__ Kr)
{
  __shared__ short As[128*32];
  __shared__ short Bs[128*32];
  const int tid  = threadIdx.x;
  const int lane = tid & 63, w = tid >> 6;
  const int wm = (w >> 1) * 64, wn = (w & 1) * 64;
  const int m0 = blockIdx.x * 128, n0 = blockIdx.y * 128;
  const int lr = lane & 15, lk = (lane >> 4) * 8;

  const int sr = tid >> 2;
  const int sc = (tid & 3) * 8;
  const short* aS = Abf + (size_t)(m0 + sr) * H_ + sc;
  const short* bS = Wt  + (size_t)(n0 + sr) * H_ + sc;
  short* aD = As + tid * 8;
  short* bD = Bs + tid * 8;

  f32x4 acc[4][4] = {};

  for(int k0 = 0; k0 < H_; k0 += 32){
    __syncthreads();
    __builtin_amdgcn_global_load_lds(GLB(aS + k0),           LDSP(aD),        16, 0, 0);
    __builtin_amdgcn_global_load_lds(GLB(aS + 64*H_ + k0),   LDSP(aD + 2048), 16, 0, 0);
    __builtin_amdgcn_global_load_lds(GLB(bS + k0),           LDSP(bD),        16, 0, 0);
    __builtin_amdgcn_global_load_lds(GLB(bS + 64*H_ + k0),   LDSP(bD + 2048), 16, 0, 0);
    __syncthreads();

    bf16x8 aF[4], bF[4];
    #pragma unroll
    for(int i = 0; i < 4; ++i) aF[i] = *(const bf16x8*)(As + (wm + i*16 + lr)*32 + lk);
    #pragma unroll
    for(int j = 0; j < 4; ++j) bF[j] = *(const bf16x8*)(Bs + (wn + j*16 + lr)*32 + lk);
    #pragma unroll
    for(int i = 0; i < 4; ++i)
      #pragma unroll
      for(int j = 0; j < 4; ++j)
        acc[i][j] = __builtin_amdgcn_mfma_f32_16x16x32_bf16(bF[j], aF[i], acc[i][j], 0, 0, 0);
  }

  // epilogue: bias + lane-local RoPE + packed 4B stores
  const int t = n0 >> 7;
  #pragma unroll
  for(int i = 0; i < 4; ++i){
    int m  = m0 + wm + i*16 + lr;
    int bi = m >> 9, sp = m & 511;
    size_t rowoff = ((size_t)(bi*T_ + t)*S_ + sp)*HD_;
    #pragma unroll
    for(int j = 0; j < 4; ++j){
      int nq  = n0 + wn + j*16 + ((lane >> 4) << 2);
      int hd0 = (nq >> 1) & 63;
      int p   = (nq >> 2) & 31;
      float4 bv = *(const float4*)(bias + nq);
      float2 cs = tab[sp*32 + p];
      float q0 = acc[i][j][0] + bv.x;
      float k0v= acc[i][j][1] + bv.y;
      float q1 = acc[i][j][2] + bv.z;
      float k1v= acc[i][j][3] + bv.w;
      float rq0 = q0*cs.x - q1*cs.y, rq1 = q1*cs.x + q0*cs.y;
      float rk0 = k0v*cs.x - k1v*cs.y, rk1 = k1v*cs.x + k0v*cs.y;
      unsigned uq = (unsigned)f2bf(rq0) | ((unsigned)f2bf(rq1) << 16);
      unsigned uk = (unsigned)f2bf(rk0) | ((unsigned)f2bf(rk1) << 16);
      *(unsigned*)(Qr + rowoff + hd0) = uq;
      *(unsigned*)(Kr + rowoff + hd0) = uk;
    }
  }
}

// --- biaffine (swapped operands): lane holds 4 consecutive n -> float4 store ---
__global__ __launch_bounds__(256) void gemm2_mask(
    const short* __restrict__ Qr, const short* __restrict__ Kr,
    const int* __restrict__ am, float* __restrict__ out)
{
  const int lane = threadIdx.x & 63;
  const int w    = threadIdx.x >> 6;
  const int bt   = blockIdx.z;
  const int b    = bt / T_;
  const int n0   = blockIdx.x * 128 + (w & 1) * 64;
  const int m0   = blockIdx.y * 128 + (w >> 1) * 64;
  const int lr   = lane & 15;
  const int lk   = (lane >> 4) * 8;

  const short* Q = Qr + (size_t)bt * S_ * HD_;
  const short* K = Kr + (size_t)bt * S_ * HD_;
  f32x4 acc[4][4] = {};

  #pragma unroll
  for(int ks = 0; ks < HD_; ks += 32){
    bf16x8 aF[4], bF[4];
    #pragma unroll
    for(int i = 0; i < 4; ++i) aF[i] = *(const bf16x8*)(Q + (size_t)(m0 + i*16 + lr)*HD_ + ks + lk);
    #pragma unroll
    for(int j = 0; j < 4; ++j) bF[j] = *(const bf16x8*)(K + (size_t)(n0 + j*16 + lr)*HD_ + ks + lk);
    #pragma unroll
    for(int i = 0; i < 4; ++i)
      #pragma unroll
      for(int j = 0; j < 4; ++j)
        acc[i][j] = __builtin_amdgcn_mfma_f32_16x16x32_bf16(bF[j], aF[i], acc[i][j], 0, 0, 0);
  }

  const int* amb = am + b * S_;
  #pragma unroll
  for(int i = 0; i < 4; ++i){
    int m = m0 + i*16 + lr;
    float amm = (float)amb[m];
    float* orow = out + ((size_t)bt*S_ + m)*S_;
    #pragma unroll
    for(int j = 0; j < 4; ++j){
      int nq = n0 + j*16 + ((lane >> 4) << 2);
      int4 a4 = *(const int4*)(amb + nq);
      float4 r;
      r.x = acc[i][j][0]*0.125f - (1.f - amm*(float)a4.x)*1e12f - ((nq+0) < m ? 1e12f : 0.f);
      r.y = acc[i][j][1]*0.125f - (1.f - amm*(float)a4.y)*1e12f - ((nq+1) < m ? 1e12f : 0.f);
      r.z = acc[i][j][2]*0.125f - (1.f - amm*(float)a4.z)*1e12f - ((nq+2) < m ? 1e12f : 0.f);
      r.w = acc[i][j][3]*0.125f - (1.f - amm*(float)a4.w)*1e12f - ((nq+3) < m ? 1e12f : 0.f);
      *(float4*)(orow + nq) = r;
    }
  }
}

extern "C" void kernel_launch(void* const* d_in, const int* in_sizes, int n_in,
                              void* d_out, int out_size, void* d_ws, size_t ws_size,
                              hipStream_t stream)
{
  const float* hs    = (const float*)d_in[0];
  const int*   amask = (const int*)  d_in[1];
  const float* W     = (const float*)d_in[2];
  const float* bias  = (const float*)d_in[3];
  float* out = (float*)d_out;

  char* ws = (char*)d_ws;
  short*  Wt  = (short*) (ws);                       // 1,769,472 B
  float2* tab = (float2*)(ws + 1769472);             //   131,072 B
  short*  Qr  = (short*) (ws + 1900544);             // 9,437,184 B
  short*  Kr  = (short*) (ws + 11337728);            // 9,437,184 B
  short*  Abf = (short*) (ws + 20774912);            // 12,582,912 B

  prep_all <<<4000, 256, 0, stream>>>(hs, Abf, W, Wt, tab);
  gemm1_rope<<<dim3(M1/128, N1/128), 256, 0, stream>>>(Abf, Wt, bias, tab, Qr, Kr);
  gemm2_mask<<<dim3(S_/128, S_/128, B_*T_), 256, 0, stream>>>(Qr, Kr, amask, out);
}

// Round 5
// 97.946 us; speedup vs baseline: 2.3078x; 1.0467x over previous
//
#include <hip/hip_runtime.h>

#define B_  16
#define S_  512
#define H_  768
#define T_  9
#define HD_ 64
#define N1  (T_*HD_*2)   // 1152
#define M1  (B_*S_)      // 8192
#define NT1 (H_/32)      // 24 K-tiles

typedef __attribute__((ext_vector_type(8))) short bf16x8;
typedef __attribute__((ext_vector_type(4))) float f32x4;

#define GLB(p) ((const __attribute__((address_space(1))) void*)(p))
#define LDSP(p) ((__attribute__((address_space(3))) void*)(p))

__device__ inline unsigned short f2bf(float f){
  union { float f; unsigned u; } v; v.f = f;
  unsigned r = v.u + 0x7fffu + ((v.u >> 16) & 1u);   // RNE
  return (unsigned short)(r >> 16);
}

// --- merged prep: hs->bf16 | W transpose->bf16 | trig table ---
__global__ __launch_bounds__(256) void prep_all(
    const float* __restrict__ hs, short* __restrict__ Abf,
    const float* __restrict__ W, short* __restrict__ Wt,
    float2* __restrict__ tab)
{
  __shared__ float tile[32][33];
  const int bx = blockIdx.x, tid = threadIdx.x;
  if(bx < 3072){
    int i = bx*2048 + tid*8;
    float4 a0 = *(const float4*)(hs + i);
    float4 a1 = *(const float4*)(hs + i + 4);
    bf16x8 r;
    r[0]=f2bf(a0.x); r[1]=f2bf(a0.y); r[2]=f2bf(a0.z); r[3]=f2bf(a0.w);
    r[4]=f2bf(a1.x); r[5]=f2bf(a1.y); r[6]=f2bf(a1.z); r[7]=f2bf(a1.w);
    *(bf16x8*)(Abf + i) = r;
  } else if(bx < 3936){
    int idx = bx - 3072;
    int n0 = (idx % 36)*32, k0 = (idx / 36)*32;
    int tx = tid & 31, ty = tid >> 5;
    #pragma unroll
    for(int r = 0; r < 32; r += 8)
      tile[ty + r][tx] = W[(size_t)(k0 + ty + r)*N1 + n0 + tx];
    __syncthreads();
    #pragma unroll
    for(int r = 0; r < 32; r += 8)
      Wt[(size_t)(n0 + ty + r)*H_ + k0 + tx] = f2bf(tile[tx][ty + r]);
  } else {
    int i = (bx - 3936)*256 + tid;
    int s = i >> 5, p = i & 31;
    float inv = powf(10000.f, -2.f*(float)p/64.f);
    float a = (float)s * inv;
    tab[i] = make_float2(cosf(a), sinf(a));
  }
}

// --- GEMM1 (prefetch 2-phase, swapped operands) + bias + RoPE -> Qr,Kr ---
__global__ __launch_bounds__(256) void gemm1_rope(
    const short* __restrict__ Abf, const short* __restrict__ Wt,
    const float* __restrict__ bias, const float2* __restrict__ tab,
    short* __restrict__ Qr, short* __restrict__ Kr)
{
  __shared__ short As[2][128*32];
  __shared__ short Bs[2][128*32];
  const int tid  = threadIdx.x;
  const int lane = tid & 63, w = tid >> 6;
  const int wm = (w >> 1) * 64, wn = (w & 1) * 64;
  const int m0 = blockIdx.x * 128, n0 = blockIdx.y * 128;
  const int lr = lane & 15, lk = (lane >> 4) * 8;

  const int sr = tid >> 2;
  const int sc = (tid & 3) * 8;
  const short* aS = Abf + (size_t)(m0 + sr) * H_ + sc;
  const short* bS = Wt  + (size_t)(n0 + sr) * H_ + sc;
  const int dOff = tid * 8;

#define STAGE1(buf, k0) do{ \
    __builtin_amdgcn_global_load_lds(GLB(aS + (k0)),         LDSP(&As[buf][dOff]),        16, 0, 0); \
    __builtin_amdgcn_global_load_lds(GLB(aS + 64*H_ + (k0)), LDSP(&As[buf][dOff + 2048]), 16, 0, 0); \
    __builtin_amdgcn_global_load_lds(GLB(bS + (k0)),         LDSP(&Bs[buf][dOff]),        16, 0, 0); \
    __builtin_amdgcn_global_load_lds(GLB(bS + 64*H_ + (k0)), LDSP(&Bs[buf][dOff + 2048]), 16, 0, 0); \
  }while(0)

  f32x4 acc[4][4] = {};
  STAGE1(0, 0);

  for(int it = 0; it < NT1; ++it){
    __syncthreads();                    // drains vmcnt(0): stage(it) resident; all waves synced
    const int cur = it & 1;
    if(it + 1 < NT1) STAGE1(cur ^ 1, (it + 1) * 32);   // prefetch hides under compute below

    bf16x8 aF[4], bF[4];
    #pragma unroll
    for(int i = 0; i < 4; ++i) aF[i] = *(const bf16x8*)(&As[cur][(wm + i*16 + lr)*32 + lk]);
    #pragma unroll
    for(int j = 0; j < 4; ++j) bF[j] = *(const bf16x8*)(&Bs[cur][(wn + j*16 + lr)*32 + lk]);
    #pragma unroll
    for(int i = 0; i < 4; ++i)
      #pragma unroll
      for(int j = 0; j < 4; ++j)
        acc[i][j] = __builtin_amdgcn_mfma_f32_16x16x32_bf16(bF[j], aF[i], acc[i][j], 0, 0, 0);
  }

  // epilogue: bias + lane-local RoPE + packed 4B stores
  const int t = n0 >> 7;
  #pragma unroll
  for(int i = 0; i < 4; ++i){
    int m  = m0 + wm + i*16 + lr;
    int bi = m >> 9, sp = m & 511;
    size_t rowoff = ((size_t)(bi*T_ + t)*S_ + sp)*HD_;
    #pragma unroll
    for(int j = 0; j < 4; ++j){
      int nq  = n0 + wn + j*16 + ((lane >> 4) << 2);
      int hd0 = (nq >> 1) & 63;
      int p   = (nq >> 2) & 31;
      float4 bv = *(const float4*)(bias + nq);
      float2 cs = tab[sp*32 + p];
      float q0 = acc[i][j][0] + bv.x;
      float k0v= acc[i][j][1] + bv.y;
      float q1 = acc[i][j][2] + bv.z;
      float k1v= acc[i][j][3] + bv.w;
      float rq0 = q0*cs.x - q1*cs.y, rq1 = q1*cs.x + q0*cs.y;
      float rk0 = k0v*cs.x - k1v*cs.y, rk1 = k1v*cs.x + k0v*cs.y;
      unsigned uq = (unsigned)f2bf(rq0) | ((unsigned)f2bf(rq1) << 16);
      unsigned uk = (unsigned)f2bf(rk0) | ((unsigned)f2bf(rk1) << 16);
      *(unsigned*)(Qr + rowoff + hd0) = uq;
      *(unsigned*)(Kr + rowoff + hd0) = uk;
    }
  }
}

// --- biaffine (swapped operands): lane holds 4 consecutive n -> float4 store ---
__global__ __launch_bounds__(256) void gemm2_mask(
    const short* __restrict__ Qr, const short* __restrict__ Kr,
    const int* __restrict__ am, float* __restrict__ out)
{
  const int lane = threadIdx.x & 63;
  const int w    = threadIdx.x >> 6;
  const int bt   = blockIdx.z;
  const int b    = bt / T_;
  const int n0   = blockIdx.x * 128 + (w & 1) * 64;
  const int m0   = blockIdx.y * 128 + (w >> 1) * 64;
  const int lr   = lane & 15;
  const int lk   = (lane >> 4) * 8;

  const short* Q = Qr + (size_t)bt * S_ * HD_;
  const short* K = Kr + (size_t)bt * S_ * HD_;
  f32x4 acc[4][4] = {};

  #pragma unroll
  for(int ks = 0; ks < HD_; ks += 32){
    bf16x8 aF[4], bF[4];
    #pragma unroll
    for(int i = 0; i < 4; ++i) aF[i] = *(const bf16x8*)(Q + (size_t)(m0 + i*16 + lr)*HD_ + ks + lk);
    #pragma unroll
    for(int j = 0; j < 4; ++j) bF[j] = *(const bf16x8*)(K + (size_t)(n0 + j*16 + lr)*HD_ + ks + lk);
    #pragma unroll
    for(int i = 0; i < 4; ++i)
      #pragma unroll
      for(int j = 0; j < 4; ++j)
        acc[i][j] = __builtin_amdgcn_mfma_f32_16x16x32_bf16(bF[j], aF[i], acc[i][j], 0, 0, 0);
  }

  const int* amb = am + b * S_;
  #pragma unroll
  for(int i = 0; i < 4; ++i){
    int m = m0 + i*16 + lr;
    float amm = (float)amb[m];
    float* orow = out + ((size_t)bt*S_ + m)*S_;
    #pragma unroll
    for(int j = 0; j < 4; ++j){
      int nq = n0 + j*16 + ((lane >> 4) << 2);
      int4 a4 = *(const int4*)(amb + nq);
      float4 r;
      r.x = acc[i][j][0]*0.125f - (1.f - amm*(float)a4.x)*1e12f - ((nq+0) < m ? 1e12f : 0.f);
      r.y = acc[i][j][1]*0.125f - (1.f - amm*(float)a4.y)*1e12f - ((nq+1) < m ? 1e12f : 0.f);
      r.z = acc[i][j][2]*0.125f - (1.f - amm*(float)a4.z)*1e12f - ((nq+2) < m ? 1e12f : 0.f);
      r.w = acc[i][j][3]*0.125f - (1.f - amm*(float)a4.w)*1e12f - ((nq+3) < m ? 1e12f : 0.f);
      *(float4*)(orow + nq) = r;
    }
  }
}

extern "C" void kernel_launch(void* const* d_in, const int* in_sizes, int n_in,
                              void* d_out, int out_size, void* d_ws, size_t ws_size,
                              hipStream_t stream)
{
  const float* hs    = (const float*)d_in[0];
  const int*   amask = (const int*)  d_in[1];
  const float* W     = (const float*)d_in[2];
  const float* bias  = (const float*)d_in[3];
  float* out = (float*)d_out;

  char* ws = (char*)d_ws;
  short*  Wt  = (short*) (ws);                       // 1,769,472 B
  float2* tab = (float2*)(ws + 1769472);             //   131,072 B
  short*  Qr  = (short*) (ws + 1900544);             // 9,437,184 B
  short*  Kr  = (short*) (ws + 11337728);            // 9,437,184 B
  short*  Abf = (short*) (ws + 20774912);            // 12,582,912 B

  prep_all <<<4000, 256, 0, stream>>>(hs, Abf, W, Wt, tab);
  gemm1_rope<<<dim3(M1/128, N1/128), 256, 0, stream>>>(Abf, Wt, bias, tab, Qr, Kr);
  gemm2_mask<<<dim3(S_/128, S_/128, B_*T_), 256, 0, stream>>>(Qr, Kr, amask, out);
}

// Round 6
// 94.420 us; speedup vs baseline: 2.3939x; 1.0373x over previous
//
#include <hip/hip_runtime.h>

#define B_  16
#define S_  512
#define H_  768
#define T_  9
#define HD_ 64
#define N1  (T_*HD_*2)   // 1152
#define M1  (B_*S_)      // 8192
#define NT1 (H_/32)      // 24 K-tiles

typedef __attribute__((ext_vector_type(8))) short bf16x8;
typedef __attribute__((ext_vector_type(4))) float f32x4;

#define GLB(p) ((const __attribute__((address_space(1))) void*)(p))
#define LDSP(p) ((__attribute__((address_space(3))) void*)(p))

__device__ inline unsigned short f2bf(float f){
  union { float f; unsigned u; } v; v.f = f;
  unsigned r = v.u + 0x7fffu + ((v.u >> 16) & 1u);   // RNE
  return (unsigned short)(r >> 16);
}

// --- prep: W [768,1152] fp32 -> Wt [1152,768] bf16 transpose | trig table ---
__global__ __launch_bounds__(256) void prep_wt(
    const float* __restrict__ W, short* __restrict__ Wt, float2* __restrict__ tab)
{
  __shared__ float tile[32][33];
  const int bx = blockIdx.x, tid = threadIdx.x;
  if(bx < 864){                       // 36 x 24 tiles of 32x32
    int n0 = (bx % 36)*32, k0 = (bx / 36)*32;
    int tx = tid & 31, ty = tid >> 5;
    #pragma unroll
    for(int r = 0; r < 32; r += 8)
      tile[ty + r][tx] = W[(size_t)(k0 + ty + r)*N1 + n0 + tx];
    __syncthreads();
    #pragma unroll
    for(int r = 0; r < 32; r += 8)
      Wt[(size_t)(n0 + ty + r)*H_ + k0 + tx] = (short)f2bf(tile[tx][ty + r]);
  } else {                            // 64 blocks: 512 x 32 trig entries
    int i = (bx - 864)*256 + tid;
    int s = i >> 5, p = i & 31;
    float inv = powf(10000.f, -2.f*(float)p/64.f);
    float a = (float)s * inv;
    tab[i] = make_float2(cosf(a), sinf(a));
  }
}

// --- GEMM1: BM=64 BN=128, fused fp32->bf16 A reg-staging, counted vmcnt ---
__global__ __launch_bounds__(256, 4) void gemm1_rope(
    const float* __restrict__ hs, const short* __restrict__ Wt,
    const float* __restrict__ bias, const float2* __restrict__ tab,
    short* __restrict__ Qr, short* __restrict__ Kr)
{
  __shared__ short As[2][64*32];      // 2 x 4 KB
  __shared__ short Bs[2][128*32];     // 2 x 8 KB
  const int tid  = threadIdx.x;
  const int lane = tid & 63, w = tid >> 6;
  const int wm = (w & 1) * 32, wn = (w >> 1) * 64;
  const int m0 = blockIdx.x * 64, n0 = blockIdx.y * 128;
  const int lr = lane & 15, lk = (lane >> 4) * 8;

  // staging coords: thread -> A row tid>>2 (0..63), k-chunk (tid&3)*8
  const int ar = tid >> 2, ac = (tid & 3) * 8;
  const float* aS = hs + (size_t)(m0 + ar) * H_ + ac;
  const short* bS = Wt + (size_t)(n0 + ar) * H_ + ac;
  const int dOff = tid * 8;           // shorts: = tid*16 bytes (linear, wave-uniform+lane*16)

  f32x4 acc[2][4] = {};
  float4 ra0, ra1;

#define CVT_DSWRITE(buf) do{ \
    bf16x8 t_; \
    t_[0]=f2bf(ra0.x); t_[1]=f2bf(ra0.y); t_[2]=f2bf(ra0.z); t_[3]=f2bf(ra0.w); \
    t_[4]=f2bf(ra1.x); t_[5]=f2bf(ra1.y); t_[6]=f2bf(ra1.z); t_[7]=f2bf(ra1.w); \
    *(bf16x8*)(&As[buf][dOff]) = t_; \
  }while(0)

#define STAGE_B(buf, k0) do{ \
    __builtin_amdgcn_global_load_lds(GLB(bS + (k0)),          LDSP(&Bs[buf][dOff]),        16, 0, 0); \
    __builtin_amdgcn_global_load_lds(GLB(bS + 64*H_ + (k0)),  LDSP(&Bs[buf][2048 + dOff]), 16, 0, 0); \
  }while(0)

  // prologue: tile 0 into buf0, tile-1 A into regs
  ra0 = *(const float4*)(aS);  ra1 = *(const float4*)(aS + 4);
  CVT_DSWRITE(0);                       // compiler waits on ra deps
  STAGE_B(0, 0);                        // vm +2
  __builtin_amdgcn_sched_barrier(0);
  ra0 = *(const float4*)(aS + 32);  ra1 = *(const float4*)(aS + 36);   // vm +2
  __builtin_amdgcn_sched_barrier(0);
  asm volatile("s_waitcnt vmcnt(2)" ::: "memory");   // B(0) resident; A(1) still flying
  asm volatile("s_waitcnt lgkmcnt(0)" ::: "memory"); // my ds_write A(0) retired
  __builtin_amdgcn_s_barrier();

  for(int k = 0; k < NT1; ++k){
    const int cur = k & 1, nxt = cur ^ 1;
    if(k + 1 < NT1){
      CVT_DSWRITE(nxt);                 // A(k+1) regs -> LDS (dep-wait automatic)
      STAGE_B(nxt, (k + 1) * 32);       // vm +2 (issued BEFORE A-loads below)
    }
    __builtin_amdgcn_sched_barrier(0);
    if(k + 2 < NT1){
      ra0 = *(const float4*)(aS + (k + 2) * 32);
      ra1 = *(const float4*)(aS + (k + 2) * 32 + 4);  // vm +2
    }
    __builtin_amdgcn_sched_barrier(0);

    bf16x8 aF[2], bF[4];
    #pragma unroll
    for(int i = 0; i < 2; ++i) aF[i] = *(const bf16x8*)(&As[cur][(wm + i*16 + lr)*32 + lk]);
    #pragma unroll
    for(int j = 0; j < 4; ++j) bF[j] = *(const bf16x8*)(&Bs[cur][(wn + j*16 + lr)*32 + lk]);
    #pragma unroll
    for(int i = 0; i < 2; ++i)
      #pragma unroll
      for(int j = 0; j < 4; ++j)
        acc[i][j] = __builtin_amdgcn_mfma_f32_16x16x32_bf16(bF[j], aF[i], acc[i][j], 0, 0, 0);

    if(k + 1 < NT1){
      if(k + 2 < NT1) asm volatile("s_waitcnt vmcnt(2)" ::: "memory"); // B(k+1) done, A(k+2) flying
      else            asm volatile("s_waitcnt vmcnt(0)" ::: "memory"); // no A-load issued: drain B
      asm volatile("s_waitcnt lgkmcnt(0)" ::: "memory");               // my ds_write visible
      __builtin_amdgcn_s_barrier();
    }
  }

  // epilogue: bias + lane-local RoPE + packed 4B stores (regs = 4 consecutive n)
  const int t = n0 >> 7;
  #pragma unroll
  for(int i = 0; i < 2; ++i){
    int m  = m0 + wm + i*16 + lr;
    int bi = m >> 9, sp = m & 511;
    size_t rowoff = ((size_t)(bi*T_ + t)*S_ + sp)*HD_;
    #pragma unroll
    for(int j = 0; j < 4; ++j){
      int nq  = n0 + wn + j*16 + ((lane >> 4) << 2);
      int hd0 = (nq >> 1) & 63;
      int p   = (nq >> 2) & 31;
      float4 bv = *(const float4*)(bias + nq);
      float2 cs = tab[sp*32 + p];
      float q0 = acc[i][j][0] + bv.x;
      float k0v= acc[i][j][1] + bv.y;
      float q1 = acc[i][j][2] + bv.z;
      float k1v= acc[i][j][3] + bv.w;
      float rq0 = q0*cs.x - q1*cs.y, rq1 = q1*cs.x + q0*cs.y;
      float rk0 = k0v*cs.x - k1v*cs.y, rk1 = k1v*cs.x + k0v*cs.y;
      unsigned uq = (unsigned)f2bf(rq0) | ((unsigned)f2bf(rq1) << 16);
      unsigned uk = (unsigned)f2bf(rk0) | ((unsigned)f2bf(rk1) << 16);
      *(unsigned*)(Qr + rowoff + hd0) = uq;
      *(unsigned*)(Kr + rowoff + hd0) = uk;
    }
  }
#undef CVT_DSWRITE
#undef STAGE_B
}

// --- biaffine (swapped operands): lane holds 4 consecutive n -> float4 store ---
__global__ __launch_bounds__(256) void gemm2_mask(
    const short* __restrict__ Qr, const short* __restrict__ Kr,
    const int* __restrict__ am, float* __restrict__ out)
{
  const int lane = threadIdx.x & 63;
  const int w    = threadIdx.x >> 6;
  const int bt   = blockIdx.z;
  const int b    = bt / T_;
  const int n0   = blockIdx.x * 128 + (w & 1) * 64;
  const int m0   = blockIdx.y * 128 + (w >> 1) * 64;
  const int lr   = lane & 15;
  const int lk   = (lane >> 4) * 8;

  const short* Q = Qr + (size_t)bt * S_ * HD_;
  const short* K = Kr + (size_t)bt * S_ * HD_;
  f32x4 acc[4][4] = {};

  #pragma unroll
  for(int ks = 0; ks < HD_; ks += 32){
    bf16x8 aF[4], bF[4];
    #pragma unroll
    for(int i = 0; i < 4; ++i) aF[i] = *(const bf16x8*)(Q + (size_t)(m0 + i*16 + lr)*HD_ + ks + lk);
    #pragma unroll
    for(int j = 0; j < 4; ++j) bF[j] = *(const bf16x8*)(K + (size_t)(n0 + j*16 + lr)*HD_ + ks + lk);
    #pragma unroll
    for(int i = 0; i < 4; ++i)
      #pragma unroll
      for(int j = 0; j < 4; ++j)
        acc[i][j] = __builtin_amdgcn_mfma_f32_16x16x32_bf16(bF[j], aF[i], acc[i][j], 0, 0, 0);
  }

  const int* amb = am + b * S_;
  #pragma unroll
  for(int i = 0; i < 4; ++i){
    int m = m0 + i*16 + lr;
    float amm = (float)amb[m];
    float* orow = out + ((size_t)bt*S_ + m)*S_;
    #pragma unroll
    for(int j = 0; j < 4; ++j){
      int nq = n0 + j*16 + ((lane >> 4) << 2);
      int4 a4 = *(const int4*)(amb + nq);
      float4 r;
      r.x = acc[i][j][0]*0.125f - (1.f - amm*(float)a4.x)*1e12f - ((nq+0) < m ? 1e12f : 0.f);
      r.y = acc[i][j][1]*0.125f - (1.f - amm*(float)a4.y)*1e12f - ((nq+1) < m ? 1e12f : 0.f);
      r.z = acc[i][j][2]*0.125f - (1.f - amm*(float)a4.z)*1e12f - ((nq+2) < m ? 1e12f : 0.f);
      r.w = acc[i][j][3]*0.125f - (1.f - amm*(float)a4.w)*1e12f - ((nq+3) < m ? 1e12f : 0.f);
      *(float4*)(orow + nq) = r;
    }
  }
}

extern "C" void kernel_launch(void* const* d_in, const int* in_sizes, int n_in,
                              void* d_out, int out_size, void* d_ws, size_t ws_size,
                              hipStream_t stream)
{
  const float* hs    = (const float*)d_in[0];
  const int*   amask = (const int*)  d_in[1];
  const float* W     = (const float*)d_in[2];
  const float* bias  = (const float*)d_in[3];
  float* out = (float*)d_out;

  char* ws = (char*)d_ws;
  short*  Wt  = (short*) (ws);                       // 1,769,472 B
  float2* tab = (float2*)(ws + 1769472);             //   131,072 B
  short*  Qr  = (short*) (ws + 1900544);             // 9,437,184 B
  short*  Kr  = (short*) (ws + 11337728);            // 9,437,184 B

  prep_wt  <<<928, 256, 0, stream>>>(W, Wt, tab);
  gemm1_rope<<<dim3(M1/64, N1/128), 256, 0, stream>>>(hs, Wt, bias, tab, Qr, Kr);
  gemm2_mask<<<dim3(S_/128, S_/128, B_*T_), 256, 0, stream>>>(Qr, Kr, amask, out);
}